// Round 1
// baseline (282.058 us; speedup 1.0000x reference)
//
#include <hip/hip_runtime.h>
#include <hip/hip_bf16.h>

#define BSZ 4
#define SEQ 2048
#define DIM 1024

typedef __attribute__((ext_vector_type(8))) short bf16x8;
typedef __attribute__((ext_vector_type(4))) float floatx4;

__device__ __forceinline__ unsigned short f2bf(float x) {
  union { float f; unsigned int u; } v; v.f = x;
  unsigned int r = v.u + 0x7fffu + ((v.u >> 16) & 1u);
  return (unsigned short)(r >> 16);
}

template <typename T> __device__ __forceinline__ void store_c(T* p, float v);
template <> __device__ __forceinline__ void store_c<float>(float* p, float v) { *p = v; }
template <> __device__ __forceinline__ void store_c<unsigned short>(unsigned short* p, float v) { *p = f2bf(v); }

// ---------------- cast fp32 -> bf16 (vectorized) ----------------
__global__ __launch_bounds__(256) void cast_e(const float* __restrict__ in,
                                              unsigned short* __restrict__ out, int n) {
  int i = (blockIdx.x * 256 + threadIdx.x) * 4;
  if (i >= n) return;
  float4 v = *(const float4*)(in + i);
  ushort4 o;
  o.x = f2bf(v.x); o.y = f2bf(v.y); o.z = f2bf(v.z); o.w = f2bf(v.w);
  *(ushort4*)(out + i) = o;
}

// ---------------- transpose + cast weights ----------------
// z=0: W_Q -> WtQK rows [0,1024); z=1: W_K -> WtQK rows [1024,2048); z=2: W_V -> WtV
// Wt[n][k] = W[k][n].  block (32,8), grid (32,32,3)
__global__ __launch_bounds__(256) void transpose_w(const float* __restrict__ Wq,
                                                   const float* __restrict__ Wk,
                                                   const float* __restrict__ Wv,
                                                   unsigned short* __restrict__ WtQK,
                                                   unsigned short* __restrict__ WtV) {
  __shared__ float tile[32][33];
  int z = blockIdx.z;
  const float* W = (z == 0) ? Wq : (z == 1) ? Wk : Wv;
  unsigned short* dst = (z == 2) ? WtV : WtQK;
  int row_off = (z == 1) ? 1024 : 0;
  int n0 = blockIdx.x * 32, k0 = blockIdx.y * 32;
  int tx = threadIdx.x, ty = threadIdx.y;
  for (int r = ty; r < 32; r += 8)
    tile[r][tx] = W[(size_t)(k0 + r) * DIM + n0 + tx];
  __syncthreads();
  for (int r = ty; r < 32; r += 8)
    dst[(size_t)(row_off + n0 + r) * DIM + k0 + tx] = f2bf(tile[tx][r]);
}

// ---------------- NT bf16 MFMA GEMM ----------------
// C[m][n] = scale * sum_k A[m][k] * B[n][k]   (both operands row-major [rows][K])
// 128x128 block tile, 4 waves (2x2), 64x64 per wave, BK=64, 16x16x32 bf16 MFMA.
// CAUSAL: 0 = none, 1 = skip tiles with n0 > m0 (scores), 2 = Keff = min(K, m0+128) (PV)
template <typename OutT, int CAUSAL>
__global__ __launch_bounds__(256) void gemm_nt(
    const unsigned short* __restrict__ A, int lda, long long strideA,
    const unsigned short* __restrict__ B, int ldb, long long strideB,
    OutT* __restrict__ C, int ldc, long long strideC,
    int Kdim, float scale) {
  int m0 = blockIdx.y * 128;
  int n0 = blockIdx.x * 128;
  if (CAUSAL == 1 && n0 > m0) return;
  int Keff = (CAUSAL == 2) ? min(Kdim, m0 + 128) : Kdim;
  A += (long long)blockIdx.z * strideA;
  B += (long long)blockIdx.z * strideB;
  C += (long long)blockIdx.z * strideC;

  __shared__ __align__(16) unsigned short As[128][72];  // 64 + 8 pad
  __shared__ __align__(16) unsigned short Bs[128][72];

  int tid = threadIdx.x;
  int lane = tid & 63;
  int wid = tid >> 6;
  int wm = (wid >> 1) * 64, wn = (wid & 1) * 64;
  int lr = lane & 15, lq = lane >> 4;

  floatx4 acc[4][4] = {};

  for (int k0 = 0; k0 < Keff; k0 += 64) {
    __syncthreads();
#pragma unroll
    for (int i = 0; i < 4; i++) {
      int s = tid + 256 * i;
      int row = s >> 3;          // 0..127
      int kc = (s & 7) * 8;      // 0..56
      *(uint4*)&As[row][kc] = *(const uint4*)(A + (size_t)(m0 + row) * lda + k0 + kc);
      *(uint4*)&Bs[row][kc] = *(const uint4*)(B + (size_t)(n0 + row) * ldb + k0 + kc);
    }
    __syncthreads();
#pragma unroll
    for (int kk = 0; kk < 64; kk += 32) {
      bf16x8 af[4], bfr[4];
      int kl = kk + lq * 8;
#pragma unroll
      for (int i = 0; i < 4; i++) af[i] = *(const bf16x8*)&As[wm + i * 16 + lr][kl];
#pragma unroll
      for (int j = 0; j < 4; j++) bfr[j] = *(const bf16x8*)&Bs[wn + j * 16 + lr][kl];
#pragma unroll
      for (int i = 0; i < 4; i++)
#pragma unroll
        for (int j = 0; j < 4; j++)
          acc[i][j] = __builtin_amdgcn_mfma_f32_16x16x32_bf16(af[i], bfr[j], acc[i][j], 0, 0, 0);
    }
  }

  // C/D layout (verified m89/m91): col = lane&15, row = (lane>>4)*4 + reg
#pragma unroll
  for (int i = 0; i < 4; i++) {
    int rbase = m0 + wm + i * 16 + lq * 4;
#pragma unroll
    for (int j = 0; j < 4; j++) {
      int col = n0 + wn + j * 16 + lr;
#pragma unroll
      for (int r = 0; r < 4; r++)
        store_c(&C[(size_t)(rbase + r) * ldc + col], acc[i][j][r] * scale);
    }
  }
}

// ---------------- causal row softmax: fp32 scores -> bf16 probs ----------------
// grid (SEQ, BSZ), block 256. Only j<=q of scores is read; probs[j>q] = 0.
__global__ __launch_bounds__(256) void softmax_causal(const float* __restrict__ scores,
                                                      unsigned short* __restrict__ probs) {
  int q = blockIdx.x;
  int b = blockIdx.y;
  const float* srow = scores + ((size_t)b * SEQ + q) * SEQ;
  unsigned short* prow = probs + ((size_t)b * SEQ + q) * SEQ;
  int valid = q + 1;
  int tid = threadIdx.x;
  __shared__ float red[4];

  float mx = -INFINITY;
  for (int i = tid; i < valid; i += 256) mx = fmaxf(mx, srow[i]);
  for (int off = 32; off; off >>= 1) mx = fmaxf(mx, __shfl_xor(mx, off, 64));
  if ((tid & 63) == 0) red[tid >> 6] = mx;
  __syncthreads();
  mx = fmaxf(fmaxf(red[0], red[1]), fmaxf(red[2], red[3]));
  __syncthreads();

  float sum = 0.0f;
  for (int i = tid; i < valid; i += 256) sum += __expf(srow[i] - mx);
  for (int off = 32; off; off >>= 1) sum += __shfl_xor(sum, off, 64);
  if ((tid & 63) == 0) red[tid >> 6] = sum;
  __syncthreads();
  sum = red[0] + red[1] + red[2] + red[3];
  float inv = 1.0f / sum;

  for (int i = tid; i < SEQ; i += 256) {
    float v = (i < valid) ? __expf(srow[i] - mx) * inv : 0.0f;
    prow[i] = f2bf(v);
  }
}

extern "C" void kernel_launch(void* const* d_in, const int* in_sizes, int n_in,
                              void* d_out, int out_size, void* d_ws, size_t ws_size,
                              hipStream_t stream) {
  const float* E  = (const float*)d_in[0];
  const float* Wq = (const float*)d_in[1];
  const float* Wk = (const float*)d_in[2];
  const float* Wv = (const float*)d_in[3];
  float* out = (float*)d_out;

  char* ws = (char*)d_ws;
  size_t off = 0;
  auto alloc = [&](size_t bytes) {
    void* p = ws + off;
    off += (bytes + 255) & ~(size_t)255;
    return p;
  };
  const size_t M_ALL = (size_t)BSZ * SEQ;                    // 8192 token rows
  unsigned short* Ebf  = (unsigned short*)alloc(M_ALL * DIM * 2);          // [8192][1024]
  unsigned short* WtQK = (unsigned short*)alloc((size_t)2 * DIM * DIM * 2); // [2048][1024]
  unsigned short* WtV  = (unsigned short*)alloc((size_t)DIM * DIM * 2);     // [1024][1024]
  unsigned short* QK   = (unsigned short*)alloc(M_ALL * 2 * DIM * 2);       // [8192][2048] (Q | K)
  unsigned short* Vt   = (unsigned short*)alloc((size_t)DIM * M_ALL * 2);   // [1024][8192]
  float*          Sc   = (float*)alloc((size_t)BSZ * SEQ * SEQ * 4);        // [4][2048][2048]
  unsigned short* Pr   = (unsigned short*)alloc((size_t)BSZ * SEQ * SEQ * 2);

  // 1. casts
  int nE = (int)(M_ALL * DIM);
  cast_e<<<dim3(nE / (256 * 4)), dim3(256), 0, stream>>>(E, Ebf, nE);
  transpose_w<<<dim3(32, 32, 3), dim3(32, 8), 0, stream>>>(Wq, Wk, Wv, WtQK, WtV);

  // 2. QK projection: [8192,1024] x [2048,1024]^T -> [8192,2048]
  gemm_nt<unsigned short, 0><<<dim3(16, 64, 1), dim3(256), 0, stream>>>(
      Ebf, DIM, 0, WtQK, DIM, 0, QK, 2 * DIM, 0, DIM, 1.0f);

  // 3. Vt projection: Vt[d][token] = sum_k WtV[d][k] * E[token][k]  -> [1024,8192]
  gemm_nt<unsigned short, 0><<<dim3(64, 8, 1), dim3(256), 0, stream>>>(
      WtV, DIM, 0, Ebf, DIM, 0, Vt, (int)M_ALL, 0, DIM, 1.0f);

  // 4. scores: per batch, Q x K^T * 1/32, skip tiles above diagonal
  gemm_nt<float, 1><<<dim3(16, 16, BSZ), dim3(256), 0, stream>>>(
      QK, 2 * DIM, (long long)SEQ * 2 * DIM,
      QK + DIM, 2 * DIM, (long long)SEQ * 2 * DIM,
      Sc, SEQ, (long long)SEQ * SEQ,
      DIM, 0.03125f /* 1/sqrt(1024) */);

  // 5. causal softmax -> bf16 probs (zeros above diagonal)
  softmax_causal<<<dim3(SEQ, BSZ), dim3(256), 0, stream>>>(Sc, Pr);

  // 6. PV: out[q][d] = sum_k P[q][k] * Vt[d][k], K limited to q-tile end
  gemm_nt<float, 2><<<dim3(8, 16, BSZ), dim3(256), 0, stream>>>(
      Pr, SEQ, (long long)SEQ * SEQ,
      Vt, (int)M_ALL, (long long)SEQ,
      out, DIM, (long long)SEQ * DIM,
      SEQ, 1.0f);
}